// Round 3
// baseline (412.658 us; speedup 1.0000x reference)
//
#include <hip/hip_runtime.h>

#define B_ROWS 4096
#define K_DIM  40960
#define H_DIM  128
#define BM     64
#define BK     64
#define KSPLIT 8
#define KCHUNK (K_DIM / KSPLIT)   // 5120
#define NT     (KCHUNK / BK)      // 80 (even)
#define MT     (B_ROWS / BM)      // 64

typedef __attribute__((ext_vector_type(4))) float f32x4;
typedef __attribute__((ext_vector_type(8))) short short8;

static_assert(KSPLIT * KCHUNK == K_DIM, "ksplit");
static_assert((NT & 1) == 0, "NT even");

// fallback accumulator (atomic path) if ws too small: [2][B_ROWS][H_DIM]
__device__ float g_acc[2u * B_ROWS * H_DIM];

__device__ __forceinline__ unsigned pkbf(float a, float b) {
  // pack 2 f32 -> 2 bf16 (RTN-even), inputs finite
  unsigned ua = __float_as_uint(a), ub = __float_as_uint(b);
  ua = (ua + 0x7fffu + ((ua >> 16) & 1u)) >> 16;
  ub = (ub + 0x7fffu + ((ub >> 16) & 1u)) & 0xffff0000u;
  return ua | ub;
}

__device__ __forceinline__ short8 pk8(f32x4 a, f32x4 b) {
  union { unsigned u[4]; short8 s; } r;
  r.u[0] = pkbf(a[0], a[1]);
  r.u[1] = pkbf(a[2], a[3]);
  r.u[2] = pkbf(b[0], b[1]);
  r.u[3] = pkbf(b[2], b[3]);
  return r.s;
}

// A (x) is consumed pure-register: lane owns its batch row (M-row = lane&15),
// 2-tile-deep prefetch, nontemporal, never touches LDS or the barrier.
// B (weights) is LDS double-buffered bf16, staged from L2, 1 light barrier
// per tile (lgkmcnt only -- vmcnt is NOT drained, so the A-stream pipelines
// across barriers).
template <bool ATOMIC>
__global__ __launch_bounds__(256, 4) void nnue_stage1(
    const float* __restrict__ x1, const float* __restrict__ x2,
    const float* __restrict__ wus, const float* __restrict__ wthem,
    float* __restrict__ part) {
  __shared__ ushort ldsB[2][H_DIM][BK];  // 32 KB

  const int t = threadIdx.x;

  // XCD decode: 64 blocks sharing a (ks,mat) weight chunk -> same XCD
  const int bid = blockIdx.x;           // 0..1023
  const int xcd = bid & 7;
  const int s   = bid >> 3;             // 0..127
  const int mt  = s & 63;
  const int g   = xcd | ((s >> 6) << 3);  // 0..15
  const int mat = g & 1;
  const int ks  = g >> 1;

  const float* __restrict__ X = mat ? x2 : x1;
  const float* __restrict__ W = mat ? wthem : wus;
  const size_t kbase = (size_t)ks * KCHUNK;

  const int lane = t & 63;
  const int w    = t >> 6;   // wave 0..3 -> N-cols w*... no: waves split N
  const int fr   = lane & 15;
  const int lhi  = lane >> 4;  // 0..3

  // ---- A: per-lane row pointer (rows wave-private: arow = mt*64+w*16+fr)
  const int arow = mt * BM + w * 16 + fr;
  const float* gA = X + (size_t)arow * K_DIM + kbase + lhi * 8;

  // ---- B staging: thread t covers rows r0+16q (+64 for half 1), slot s0
  const int r0   = t >> 4;      // 0..15
  const int slot = t & 15;      // f32x4 slot in BK
  const float* gBq[4];
  #pragma unroll
  for (int q = 0; q < 4; ++q)
    gBq[q] = W + (size_t)(r0 + 16 * q) * K_DIM + kbase + slot * 4;
  // LDS write byte offset (q/h/buf added as immediates)
  const int wb0 = r0 * 128 + ((((slot >> 1) ^ (r0 & 7)) << 4)) + ((slot & 1) << 3);

  // ---- B fragment read offset: row=j*16+fr, 16B-slot=(kb*4+lhi)^(fr&7)
  const int offb0 = fr * 128 + ((lhi ^ (fr & 7)) << 4);  // kb=0
  const int offb1 = offb0 ^ 64;                          // kb=1 (bit6 toggle)

  char* ldsbase = (char*)(&ldsB[0][0][0]);

  f32x4 acc[8] = {};      // 8 j-tiles of 16x16, 4 f32 each
  f32x4 rawA[4], rawB[4]; // A 2-deep register pipeline
  f32x4 btmp[4];          // B half-tile staging

#define LOADA(raw_, kt_)                                                    \
  do {                                                                      \
    const float* pa = gA + (size_t)(kt_)*BK;                                \
    raw_[0] = __builtin_nontemporal_load((const f32x4*)(pa));               \
    raw_[1] = __builtin_nontemporal_load((const f32x4*)(pa + 4));           \
    raw_[2] = __builtin_nontemporal_load((const f32x4*)(pa + 32));          \
    raw_[3] = __builtin_nontemporal_load((const f32x4*)(pa + 36));          \
  } while (0)

#define LOADB_H(h_, kt_)                                                    \
  do {                                                                      \
    _Pragma("unroll") for (int q = 0; q < 4; ++q)                           \
        btmp[q] = *(const f32x4*)(gBq[q] + (size_t)(h_)*64 * K_DIM +        \
                                  (size_t)(kt_)*BK);                        \
  } while (0)

#define STAGEB_H(h_, buf_)                                                  \
  do {                                                                      \
    _Pragma("unroll") for (int q = 0; q < 4; ++q) {                         \
      uint2 p;                                                              \
      p.x = pkbf(btmp[q][0], btmp[q][1]);                                   \
      p.y = pkbf(btmp[q][2], btmp[q][3]);                                   \
      *(uint2*)(ldsbase + wb0 + q * 2048 + (h_)*8192 + (buf_)*16384) = p;   \
    }                                                                       \
  } while (0)

#define MFMA_KB(buf_, af_, OFFB_)                                           \
  do {                                                                      \
    _Pragma("unroll") for (int j = 0; j < 8; ++j) {                         \
      short8 bg =                                                           \
          *(const short8*)(ldsbase + (OFFB_) + j * 2048 + (buf_)*16384);    \
      acc[j] =                                                              \
          __builtin_amdgcn_mfma_f32_16x16x32_bf16(af_, bg, acc[j], 0, 0, 0);\
    }                                                                       \
  } while (0)

  // light barrier: drain LDS ops only; vmcnt (A-stream) rides through
#define BARRIER()                                                           \
  do {                                                                      \
    asm volatile("s_waitcnt lgkmcnt(0)" ::: "memory");                      \
    __builtin_amdgcn_s_barrier();                                           \
    __builtin_amdgcn_sched_barrier(0);                                      \
  } while (0)

#define TILE(raw_, BUFC_, BUFN_, ktn_, kta_, DO_A, DO_B)                    \
  do {                                                                      \
    short8 af0 = pk8(raw_[0], raw_[1]);                                     \
    short8 af1 = pk8(raw_[2], raw_[3]);                                     \
    if (DO_A) LOADA(raw_, kta_);                                            \
    if (DO_B) LOADB_H(0, ktn_);                                             \
    MFMA_KB(BUFC_, af0, offb0);                                             \
    if (DO_B) {                                                             \
      STAGEB_H(0, BUFN_);                                                   \
      LOADB_H(1, ktn_);                                                     \
    }                                                                       \
    MFMA_KB(BUFC_, af1, offb1);                                             \
    if (DO_B) {                                                             \
      STAGEB_H(1, BUFN_);                                                   \
      BARRIER();                                                            \
    }                                                                       \
  } while (0)

  // prologue: A tiles 0,1 in flight; B tile 0 staged
  LOADA(rawA, 0);
  LOADA(rawB, 1);
  LOADB_H(0, 0);
  STAGEB_H(0, 0);
  LOADB_H(1, 0);
  STAGEB_H(1, 0);
  BARRIER();

  for (int kt = 0; kt < NT - 2; kt += 2) {
    TILE(rawA, 0, 1, kt + 1, kt + 2, true, true);
    TILE(rawB, 1, 0, kt + 2, kt + 3, true, true);
  }
  // tail: tiles NT-2 (buf0, rawA) and NT-1 (buf1, rawB)
  TILE(rawA, 0, 1, NT - 1, 0, false, true);
  TILE(rawB, 1, 0, 0, 0, false, false);

#undef LOADA
#undef LOADB_H
#undef STAGEB_H
#undef MFMA_KB
#undef BARRIER
#undef TILE

  // ---- epilogue: C/D layout col(N)=lane&15, row(M)=(lane>>4)*4+reg
  if (!ATOMIC) {
    float* dst = part + (((size_t)mat * KSPLIT + ks) * B_ROWS) * (size_t)H_DIM;
    #pragma unroll
    for (int j = 0; j < 8; ++j)
      #pragma unroll
      for (int r = 0; r < 4; ++r) {
        const int rowg = mt * BM + w * 16 + (lhi << 2) + r;
        const int colg = j * 16 + fr;
        __builtin_nontemporal_store(acc[j][r],
                                    &dst[(size_t)rowg * H_DIM + colg]);
      }
  } else {
    float* dst = g_acc + (size_t)mat * B_ROWS * H_DIM;
    #pragma unroll
    for (int j = 0; j < 8; ++j)
      #pragma unroll
      for (int r = 0; r < 4; ++r) {
        const int rowg = mt * BM + w * 16 + (lhi << 2) + r;
        const int colg = j * 16 + fr;
        atomicAdd(&dst[(size_t)rowg * H_DIM + colg], acc[j][r]);
      }
  }
}

__global__ void nnue_zero_acc() {
  const unsigned i = blockIdx.x * 256 + threadIdx.x;
  if (i < 2u * B_ROWS * H_DIM) g_acc[i] = 0.f;
}

// one wave per output row; part==nullptr -> read g_acc (KS must be 1)
template <int KS>
__global__ __launch_bounds__(512) void nnue_stage2(
    const float* __restrict__ part, const float* __restrict__ w2,
    float* __restrict__ out) {
  const float* p = part ? part : (const float*)g_acc;
  const int t = threadIdx.x;
  const int l = t & 63, w = t >> 6;
  const int b = blockIdx.x * 8 + w;
  float a0 = 0.f, a1 = 0.f, a2 = 0.f, a3 = 0.f;
  #pragma unroll
  for (int ks = 0; ks < KS; ++ks) {
    const float* p0 = p + ((size_t)ks * B_ROWS + b) * H_DIM;
    const float* p1 = p + (((size_t)KS + ks) * B_ROWS + b) * H_DIM;
    a0 += __builtin_nontemporal_load(&p0[l]);
    a1 += __builtin_nontemporal_load(&p0[l + 64]);
    a2 += __builtin_nontemporal_load(&p1[l]);
    a3 += __builtin_nontemporal_load(&p1[l + 64]);
  }
  float sv = fmaxf(a0, 0.f) * w2[l] + fmaxf(a1, 0.f) * w2[l + 64] +
             fmaxf(a2, 0.f) * w2[l + 128] + fmaxf(a3, 0.f) * w2[l + 192];
  #pragma unroll
  for (int off = 32; off; off >>= 1) sv += __shfl_xor(sv, off, 64);
  if (l == 0) out[b] = sv;
}

extern "C" void kernel_launch(void* const* d_in, const int* in_sizes, int n_in,
                              void* d_out, int out_size, void* d_ws,
                              size_t ws_size, hipStream_t stream) {
  const float* x1    = (const float*)d_in[0];
  const float* x2    = (const float*)d_in[1];
  // d_in[2] = turn (unused by reference)
  const float* wus   = (const float*)d_in[3];
  const float* wthem = (const float*)d_in[4];
  const float* w2    = (const float*)d_in[5];
  float* out = (float*)d_out;

  const size_t PART_BYTES =
      2ull * KSPLIT * B_ROWS * H_DIM * sizeof(float);  // 32 MiB

  if (ws_size >= PART_BYTES) {
    float* part = (float*)d_ws;
    nnue_stage1<false><<<MT * KSPLIT * 2, 256, 0, stream>>>(x1, x2, wus, wthem,
                                                            part);
    nnue_stage2<KSPLIT><<<B_ROWS / 8, 512, 0, stream>>>(part, w2, out);
  } else {
    nnue_zero_acc<<<(2 * B_ROWS * H_DIM + 255) / 256, 256, 0, stream>>>();
    nnue_stage1<true><<<MT * KSPLIT * 2, 256, 0, stream>>>(x1, x2, wus, wthem,
                                                           nullptr);
    nnue_stage2<1><<<B_ROWS / 8, 512, 0, stream>>>(nullptr, w2, out);
  }
}